// Round 9
// baseline (40098.676 us; speedup 1.0000x reference)
//
#include <hip/hip_runtime.h>
#include <hip/hip_bf16.h>

// R9: production = v5 (best, 16.9ms) + v6's conflict-free y0 staging.
// PLUS 4 ablation probes (scratch-only) to decompose the per-step cost:
//   probe_compute  : dots+gates+stage+syncs, NO exchange      (4096 steps)
//   probe_exch128  : tagged publish+poll only, 128 WGs        (2048 steps)
//   probe_exch64   : tagged publish+poll only, 64 WGs         (2048 steps)
//   probe_exch_xcd : volatile L2 publish+poll, 32 WGs, 1 XCD  (4096 steps)
// Read each probe's dur_us from rocprof next round.

#define TT    4096
#define HDIM  1024
#define L0WG  64
#define L1WG  128
#define SBS   512
#define FSTR  16
typedef unsigned short ushort_t;
typedef unsigned long long u64;

// ---------------- embedding gather ----------------
__global__ void embed_kernel(const int* __restrict__ idx,
                             const float* __restrict__ emb,
                             float* __restrict__ x) {
    int t = blockIdx.x;
    int row = idx[t];
    const float4* src = reinterpret_cast<const float4*>(emb + (size_t)row * HDIM);
    float4* dst = reinterpret_cast<float4*>(x + (size_t)t * HDIM);
    dst[threadIdx.x] = src[threadIdx.x];
}

// ---------------- fp32 NT GEMM ----------------
#define BM 64
#define BN 64
#define BK 32
__global__ __launch_bounds__(256)
void gemm_nt_bias(const float* __restrict__ A,
                  const float* __restrict__ Bw,
                  const float* __restrict__ bias,
                  float* __restrict__ C,
                  int M, int N, int K) {
    __shared__ float As[BK][BM];
    __shared__ float Bs[BK][BN];
    const int tid = threadIdx.x;
    const int m0 = blockIdx.x * BM;
    const int n0 = blockIdx.y * BN;
    const int tx = tid & 15, ty = tid >> 4;
    const int lr = tid >> 3;
    const int lc = (tid & 7) * 4;

    float acc[4][4] = {};

    for (int k0 = 0; k0 < K; k0 += BK) {
#pragma unroll
        for (int pass = 0; pass < 2; ++pass) {
            int m = lr + pass * 32;
            float4 v = *reinterpret_cast<const float4*>(A + (size_t)(m0 + m) * K + k0 + lc);
            As[lc + 0][m] = v.x; As[lc + 1][m] = v.y;
            As[lc + 2][m] = v.z; As[lc + 3][m] = v.w;
            float4 u = *reinterpret_cast<const float4*>(Bw + (size_t)(n0 + m) * K + k0 + lc);
            Bs[lc + 0][m] = u.x; Bs[lc + 1][m] = u.y;
            Bs[lc + 2][m] = u.z; Bs[lc + 3][m] = u.w;
        }
        __syncthreads();
#pragma unroll
        for (int kk = 0; kk < BK; ++kk) {
            float4 a = *reinterpret_cast<const float4*>(&As[kk][ty * 4]);
            float4 b = *reinterpret_cast<const float4*>(&Bs[kk][tx * 4]);
            float av[4] = {a.x, a.y, a.z, a.w};
            float bv[4] = {b.x, b.y, b.z, b.w};
#pragma unroll
            for (int i = 0; i < 4; ++i)
#pragma unroll
                for (int j = 0; j < 4; ++j)
                    acc[i][j] = fmaf(av[i], bv[j], acc[i][j]);
        }
        __syncthreads();
    }

    float4 b4 = *reinterpret_cast<const float4*>(bias + n0 + tx * 4);
    float bb[4] = {b4.x, b4.y, b4.z, b4.w};
#pragma unroll
    for (int i = 0; i < 4; ++i) {
        int m = m0 + ty * 4 + i;
        float4 o;
        o.x = acc[i][0] + bb[0];
        o.y = acc[i][1] + bb[1];
        o.z = acc[i][2] + bb[2];
        o.w = acc[i][3] + bb[3];
        *reinterpret_cast<float4*>(C + (size_t)m * N + n0 + tx * 4) = o;
    }
}

// ---------------- helpers ----------------
__device__ __forceinline__ float dot4(float4 a, float4 b) {
    return fmaf(a.x, b.x, fmaf(a.y, b.y, fmaf(a.z, b.z, a.w * b.w)));
}
__device__ __forceinline__ float fsig(float x) { return 1.f / (1.f + __expf(-x)); }
__device__ __forceinline__ float ftanh(float x) {
    return fmaf(-2.f, 1.f / (1.f + __expf(2.f * x)), 1.f);
}
__device__ __forceinline__ float bflo(unsigned u) { return __uint_as_float(u << 16); }
__device__ __forceinline__ float bfhi(unsigned u) { return __uint_as_float(u & 0xffff0000u); }
__device__ __forceinline__ ushort_t f2bf(float f) {
    unsigned u = __float_as_uint(f);
    return (ushort_t)((u + 0x7FFFu + ((u >> 16) & 1u)) >> 16);
}
__device__ __forceinline__ u64 pack_h(unsigned seq, float h) {
    return ((u64)seq << 32) | (u64)__float_as_uint(h);
}
__device__ __forceinline__ u64 poll_h(const u64* p, unsigned need) {
    u64 v = __hip_atomic_load(p, __ATOMIC_RELAXED, __HIP_MEMORY_SCOPE_AGENT);
    while ((unsigned)(v >> 32) < need)
        v = __hip_atomic_load(p, __ATOMIC_RELAXED, __HIP_MEMORY_SCOPE_AGENT);
    return v;
}

// ---------------- production scan (v5 + staging fix) ----------------
__global__ __launch_bounds__(SBS, 1)
void gru_pipe(const float* __restrict__ gi0,
              const float* __restrict__ whh0,
              const float* __restrict__ bhh0,
              const float* __restrict__ wih1,
              const float* __restrict__ whh1,
              const float* __restrict__ bih1,
              const float* __restrict__ bhh1,
              float* ys0,
              float* __restrict__ out,
              u64* h0t, u64* h1t,
              unsigned* flags0) {
    const int tid  = threadIdx.x;
    const int slot = tid >> 3;
    const int l8   = tid & 7;

    __shared__ float lds_h[HDIM];
    __shared__ float lds_y[HDIM];
    __shared__ float lds_gh[48];

    if (blockIdx.x < L0WG) {
        const int g = blockIdx.x;

        float4 Wlo[16], Whi[16];
        if (slot < 48) {
            const int q = slot >> 4, jl = slot & 15;
            const float4* row4 = reinterpret_cast<const float4*>(
                whh0 + (size_t)(q * HDIM + g * 16 + jl) * HDIM);
#pragma unroll
            for (int k4 = 0; k4 < 16; ++k4) Wlo[k4] = row4[k4 * 8 + l8];
#pragma unroll
            for (int k4 = 0; k4 < 16; ++k4) Whi[k4] = row4[(k4 + 16) * 8 + l8];
        } else {
#pragma unroll
            for (int k4 = 0; k4 < 16; ++k4) { Wlo[k4] = float4{0,0,0,0}; Whi[k4] = float4{0,0,0,0}; }
        }

        float bh0 = 0.f, bh1 = 0.f, bh2 = 0.f;
        float gir = 0.f, giz = 0.f, gin = 0.f;
        float h_own = 0.f;
        if (tid < 16) {
            const int gj = g * 16 + tid;
            bh0 = bhh0[0 * HDIM + gj];
            bh1 = bhh0[1 * HDIM + gj];
            bh2 = bhh0[2 * HDIM + gj];
            gir = gi0[gj];
            giz = gi0[HDIM + gj];
            gin = gi0[2 * HDIM + gj];
        }

        lds_h[tid] = 0.f;
        lds_h[tid + SBS] = 0.f;
        __syncthreads();

        const float4* lh4 = reinterpret_cast<const float4*>(lds_h);

        for (int t = 0; t < TT; ++t) {
            float nir = 0.f, niz = 0.f, nin = 0.f;
            if (tid < 16 && t + 1 < TT) {
                const float* base = gi0 + (size_t)(t + 1) * 3 * HDIM + g * 16 + tid;
                nir = base[0];
                niz = base[HDIM];
                nin = base[2 * HDIM];
            }

            if (slot < 48) {
                float p0 = 0.f, p1 = 0.f;
#pragma unroll
                for (int k4 = 0; k4 < 16; ++k4) p0 += dot4(Wlo[k4], lh4[k4 * 8 + l8]);
#pragma unroll
                for (int k4 = 0; k4 < 16; ++k4) p1 += dot4(Whi[k4], lh4[(k4 + 16) * 8 + l8]);
                float p = p0 + p1;
                p += __shfl_xor(p, 1);
                p += __shfl_xor(p, 2);
                p += __shfl_xor(p, 4);
                if (l8 == 0) lds_gh[slot] = p;
            }
            __syncthreads();

            if (tid < 16) {
                const int gj = g * 16 + tid;
                const float hr = lds_gh[tid]      + bh0;
                const float hz = lds_gh[16 + tid] + bh1;
                const float hn = lds_gh[32 + tid] + bh2;
                const float r = fsig(gir + hr);
                const float z = fsig(giz + hz);
                const float n = ftanh(gin + r * hn);
                const float h_new = (1.f - z) * n + z * h_own;
                h_own = h_new;
                __hip_atomic_store(h0t + ((t + 1) & 1) * HDIM + gj,
                                   pack_h((unsigned)(t + 1), h_new),
                                   __ATOMIC_RELAXED, __HIP_MEMORY_SCOPE_AGENT);
                __hip_atomic_store(ys0 + (size_t)t * HDIM + gj, h_new,
                                   __ATOMIC_RELAXED, __HIP_MEMORY_SCOPE_AGENT);
                if (t == TT - 1) out[(size_t)TT * HDIM + gj] = h_new;
            }
            if (tid == 0) {
                __threadfence();
                __hip_atomic_store(flags0 + (t & 1) * (L0WG * FSTR) + g * FSTR,
                                   (unsigned)(t + 1),
                                   __ATOMIC_RELAXED, __HIP_MEMORY_SCOPE_AGENT);
            }

            {
                const unsigned need = (unsigned)(t + 1);
                const u64* hp = h0t + ((t + 1) & 1) * HDIM;
                u64 v0 = poll_h(hp + 2 * tid, need);
                u64 v1 = poll_h(hp + 2 * tid + 1, need);
                float2 hv;
                hv.x = __uint_as_float((unsigned)v0);
                hv.y = __uint_as_float((unsigned)v1);
                reinterpret_cast<float2*>(lds_h)[tid] = hv;
            }
            gir = nir; giz = niz; gin = nin;
            __syncthreads();
        }
    } else {
        const int g1 = blockIdx.x - L0WG;

        float4 Wlo[16], Whi[16];
        if (slot < 48) {
            const int ss = (slot < 24) ? slot : slot - 24;
            const int q = ss >> 3, jl = ss & 7;
            const float* mat = (slot < 24) ? whh1 : wih1;
            const float4* row4 = reinterpret_cast<const float4*>(
                mat + (size_t)(q * HDIM + g1 * 8 + jl) * HDIM);
#pragma unroll
            for (int k4 = 0; k4 < 16; ++k4) Wlo[k4] = row4[k4 * 8 + l8];
#pragma unroll
            for (int k4 = 0; k4 < 16; ++k4) Whi[k4] = row4[(k4 + 16) * 8 + l8];
        } else {
#pragma unroll
            for (int k4 = 0; k4 < 16; ++k4) { Wlo[k4] = float4{0,0,0,0}; Whi[k4] = float4{0,0,0,0}; }
        }

        float bh0 = 0.f, bh1 = 0.f, bh2 = 0.f;
        float bi0 = 0.f, bi1 = 0.f, bi2 = 0.f;
        float h_own = 0.f;
        if (tid < 8) {
            const int u = g1 * 8 + tid;
            bh0 = bhh1[0 * HDIM + u];
            bh1 = bhh1[1 * HDIM + u];
            bh2 = bhh1[2 * HDIM + u];
            bi0 = bih1[0 * HDIM + u];
            bi1 = bih1[1 * HDIM + u];
            bi2 = bih1[2 * HDIM + u];
        }

        lds_h[tid] = 0.f;
        lds_h[tid + SBS] = 0.f;
        if (tid >= 448) {
            const int l = tid - 448;
            const unsigned* f = flags0 + 0 * (L0WG * FSTR) + l * FSTR;
            while (__hip_atomic_load(f, __ATOMIC_RELAXED, __HIP_MEMORY_SCOPE_AGENT) < 1u)
                __builtin_amdgcn_s_sleep(1);
            const u64* ysrc = reinterpret_cast<const u64*>(ys0);
#pragma unroll
            for (int k = 0; k < 8; ++k) {
                u64 yv = __hip_atomic_load(ysrc + k * 64 + l, __ATOMIC_RELAXED,
                                           __HIP_MEMORY_SCOPE_AGENT);
                float2 yf;
                yf.x = __uint_as_float((unsigned)yv);
                yf.y = __uint_as_float((unsigned)(yv >> 32));
                reinterpret_cast<float2*>(lds_y)[k * 64 + l] = yf;
            }
        }
        __syncthreads();

        const float4* lh4 = reinterpret_cast<const float4*>(lds_h);
        const float4* ly4 = reinterpret_cast<const float4*>(lds_y);

        for (int t = 0; t < TT; ++t) {
            if (slot < 48) {
                const float4* s4 = (slot < 24) ? lh4 : ly4;
                float p0 = 0.f, p1 = 0.f;
#pragma unroll
                for (int k4 = 0; k4 < 16; ++k4) p0 += dot4(Wlo[k4], s4[k4 * 8 + l8]);
#pragma unroll
                for (int k4 = 0; k4 < 16; ++k4) p1 += dot4(Whi[k4], s4[(k4 + 16) * 8 + l8]);
                float p = p0 + p1;
                p += __shfl_xor(p, 1);
                p += __shfl_xor(p, 2);
                p += __shfl_xor(p, 4);
                if (l8 == 0) lds_gh[slot] = p;
            }
            __syncthreads();

            if (tid < 8) {
                const int u = g1 * 8 + tid;
                const float hr = lds_gh[tid]      + bh0;
                const float hz = lds_gh[8 + tid]  + bh1;
                const float hn = lds_gh[16 + tid] + bh2;
                const float ir = lds_gh[24 + tid] + bi0;
                const float iz = lds_gh[32 + tid] + bi1;
                const float in_ = lds_gh[40 + tid] + bi2;
                const float r = fsig(ir + hr);
                const float z = fsig(iz + hz);
                const float n = ftanh(in_ + r * hn);
                const float h_new = (1.f - z) * n + z * h_own;
                h_own = h_new;
                __hip_atomic_store(h1t + ((t + 1) & 1) * HDIM + u,
                                   pack_h((unsigned)(t + 1), h_new),
                                   __ATOMIC_RELAXED, __HIP_MEMORY_SCOPE_AGENT);
                out[(size_t)t * HDIM + u] = h_new;
                if (t == TT - 1) out[(size_t)TT * HDIM + HDIM + u] = h_new;
            }

            if (tid >= 448 && t + 1 < TT) {
                const int l = tid - 448;
                const unsigned* f = flags0 + ((t + 1) & 1) * (L0WG * FSTR) + l * FSTR;
                while (__hip_atomic_load(f, __ATOMIC_RELAXED, __HIP_MEMORY_SCOPE_AGENT)
                       < (unsigned)(t + 2)) { }
                const u64* ysrc =
                    reinterpret_cast<const u64*>(ys0 + (size_t)(t + 1) * HDIM);
#pragma unroll
                for (int k = 0; k < 8; ++k) {
                    u64 yv = __hip_atomic_load(ysrc + k * 64 + l, __ATOMIC_RELAXED,
                                               __HIP_MEMORY_SCOPE_AGENT);
                    float2 yf;
                    yf.x = __uint_as_float((unsigned)yv);
                    yf.y = __uint_as_float((unsigned)(yv >> 32));
                    reinterpret_cast<float2*>(lds_y)[k * 64 + l] = yf;
                }
            }

            {
                const unsigned need = (unsigned)(t + 1);
                const u64* hp = h1t + ((t + 1) & 1) * HDIM;
                u64 v0 = poll_h(hp + 2 * tid, need);
                u64 v1 = poll_h(hp + 2 * tid + 1, need);
                float2 hv;
                hv.x = __uint_as_float((unsigned)v0);
                hv.y = __uint_as_float((unsigned)v1);
                reinterpret_cast<float2*>(lds_h)[tid] = hv;
            }
            __syncthreads();
        }
    }
}

// ================= PROBES (scratch-only, diagnostic) =================

// probe_compute: v8-style dual bf16-LDS dots + gates + stage, NO exchange.
__global__ __launch_bounds__(SBS, 1)
void probe_compute(const float* __restrict__ whh,
                   const float* __restrict__ wih,
                   const float* __restrict__ x,
                   float* __restrict__ sink) {
    const int g   = blockIdx.x;          // 0..127
    const int u0  = (g & 127) * 8;
    const int tid = threadIdx.x;
    const int wv  = tid >> 6;
    const int ln  = tid & 63;

    __shared__ __align__(16) ushort_t lds_wh[24 * HDIM];
    __shared__ __align__(16) ushort_t lds_wi[24 * HDIM];
    __shared__ __align__(16) float lds_hf[HDIM];
    __shared__ __align__(16) float lds_y[2][HDIM];
    __shared__ float lds_gi[2][24];
    __shared__ float lds_gh[24];

    // load + convert weight slices
    for (int i = tid; i < 24 * 256; i += SBS) {   // 24 rows x 256 u32 (4 bf16 each... 2 f32->1 u32)
        const int r = i >> 8, c = i & 255;        // c indexes float2 pairs
        const size_t gr = (size_t)((r >> 3) * HDIM + u0 + (r & 7)) * HDIM;
        float2 a = reinterpret_cast<const float2*>(whh + gr)[c];
        reinterpret_cast<unsigned*>(lds_wh)[r * 512 + c] =
            (unsigned)f2bf(a.x) | ((unsigned)f2bf(a.y) << 16);
        float2 b = reinterpret_cast<const float2*>(wih + gr)[c];
        reinterpret_cast<unsigned*>(lds_wi)[r * 512 + c] =
            (unsigned)f2bf(b.x) | ((unsigned)f2bf(b.y) << 16);
    }
    reinterpret_cast<float2*>(lds_hf)[tid] = float2{0.01f, 0.01f};
    reinterpret_cast<float2*>(lds_y[0])[tid] = float2{0.01f, 0.01f};
    reinterpret_cast<float2*>(lds_y[1])[tid] = float2{0.01f, 0.01f};
    float h_own = 0.f;
    __syncthreads();

    for (int t = 0; t < TT; ++t) {
        if (wv < 3) {
            const float4* lh4 = reinterpret_cast<const float4*>(lds_hf);
            float4 hA = lh4[ln], hB = lh4[64 + ln], hC = lh4[128 + ln], hD = lh4[192 + ln];
            const uint2* wh2 = reinterpret_cast<const uint2*>(lds_wh);
#pragma unroll
            for (int rr = 0; rr < 8; ++rr) {
                const int row = wv * 8 + rr;
                const uint2* wr = wh2 + row * 256;
                uint2 w0 = wr[ln], w1 = wr[64 + ln], w2 = wr[128 + ln], w3 = wr[192 + ln];
                float p = 0.f;
                p = fmaf(bflo(w0.x), hA.x, p); p = fmaf(bfhi(w0.x), hA.y, p);
                p = fmaf(bflo(w0.y), hA.z, p); p = fmaf(bfhi(w0.y), hA.w, p);
                p = fmaf(bflo(w1.x), hB.x, p); p = fmaf(bfhi(w1.x), hB.y, p);
                p = fmaf(bflo(w1.y), hB.z, p); p = fmaf(bfhi(w1.y), hB.w, p);
                p = fmaf(bflo(w2.x), hC.x, p); p = fmaf(bfhi(w2.x), hC.y, p);
                p = fmaf(bflo(w2.y), hC.z, p); p = fmaf(bfhi(w2.y), hC.w, p);
                p = fmaf(bflo(w3.x), hD.x, p); p = fmaf(bfhi(w3.x), hD.y, p);
                p = fmaf(bflo(w3.y), hD.z, p); p = fmaf(bfhi(w3.y), hD.w, p);
                p += __shfl_xor(p, 1);  p += __shfl_xor(p, 2);
                p += __shfl_xor(p, 4);  p += __shfl_xor(p, 8);
                p += __shfl_xor(p, 16); p += __shfl_xor(p, 32);
                if (ln == 0) lds_gh[row] = p;
            }
        } else if (wv < 6) {
            const float4* ly4 = reinterpret_cast<const float4*>(lds_y[(t + 1) & 1]);
            float4 yA = ly4[ln], yB = ly4[64 + ln], yC = ly4[128 + ln], yD = ly4[192 + ln];
            const uint2* wi2 = reinterpret_cast<const uint2*>(lds_wi);
#pragma unroll
            for (int rr = 0; rr < 8; ++rr) {
                const int row = (wv - 3) * 8 + rr;
                const uint2* wr = wi2 + row * 256;
                uint2 w0 = wr[ln], w1 = wr[64 + ln], w2 = wr[128 + ln], w3 = wr[192 + ln];
                float p = 0.f;
                p = fmaf(bflo(w0.x), yA.x, p); p = fmaf(bfhi(w0.x), yA.y, p);
                p = fmaf(bflo(w0.y), yA.z, p); p = fmaf(bfhi(w0.y), yA.w, p);
                p = fmaf(bflo(w1.x), yB.x, p); p = fmaf(bfhi(w1.x), yB.y, p);
                p = fmaf(bflo(w1.y), yB.z, p); p = fmaf(bfhi(w1.y), yB.w, p);
                p = fmaf(bflo(w2.x), yC.x, p); p = fmaf(bfhi(w2.x), yC.y, p);
                p = fmaf(bflo(w2.y), yC.z, p); p = fmaf(bfhi(w2.y), yC.w, p);
                p = fmaf(bflo(w3.x), yD.x, p); p = fmaf(bfhi(w3.x), yD.y, p);
                p = fmaf(bflo(w3.y), yD.z, p); p = fmaf(bfhi(w3.y), yD.w, p);
                p += __shfl_xor(p, 1);  p += __shfl_xor(p, 2);
                p += __shfl_xor(p, 4);  p += __shfl_xor(p, 8);
                p += __shfl_xor(p, 16); p += __shfl_xor(p, 32);
                if (ln == 0) lds_gi[(t + 1) & 1][row] = p;
            }
        } else if (wv == 6) {
            const float* xs = x + (size_t)(t & 2047) * HDIM;
            const u64* s8 = reinterpret_cast<const u64*>(xs);
            u64* d8 = reinterpret_cast<u64*>(lds_y[t & 1]);
#pragma unroll
            for (int k = 0; k < 8; ++k)
                d8[k * 64 + ln] = s8[k * 64 + ln];
        }
        __syncthreads();

        if (tid < 8) {
            const float r = fsig(lds_gi[t & 1][tid] + lds_gh[tid]);
            const float z = fsig(lds_gi[t & 1][8 + tid] + lds_gh[8 + tid]);
            const float n = ftanh(lds_gi[t & 1][16 + tid] + r * lds_gh[16 + tid]);
            const float h_new = (1.f - z) * n + z * h_own;
            h_own = h_new;
            lds_hf[u0 + tid] = h_new;   // LOCAL update only (no exchange)
        }
        __syncthreads();
    }
    if (tid == 0) sink[g] = h_own + lds_hf[u0] + lds_gh[0];
}

// probe_exch128 / 64: publish+poll only.
__global__ __launch_bounds__(SBS, 1)
void probe_exch128(u64* ht, float* __restrict__ sink) {
    const int g = blockIdx.x;      // 128 WGs, 8 units each
    const int u0 = g * 8;
    const int tid = threadIdx.x;
    float h_own = (float)g;
    unsigned acc = 0;
    for (int t = 0; t < 2048; ++t) {
        __syncthreads();
        if (tid < 8) {
            h_own = fmaf(h_own, 0.5f, 1.f);
            __hip_atomic_store(ht + ((t + 1) & 1) * HDIM + u0 + tid,
                               pack_h((unsigned)(t + 1), h_own),
                               __ATOMIC_RELAXED, __HIP_MEMORY_SCOPE_AGENT);
        }
        const unsigned need = (unsigned)(t + 1);
        const u64* hp = ht + ((t + 1) & 1) * HDIM;
        u64 v0 = poll_h(hp + 2 * tid, need);
        u64 v1 = poll_h(hp + 2 * tid + 1, need);
        acc += (unsigned)v0 + (unsigned)v1;
        __syncthreads();
    }
    if (tid == 0) sink[128 + g] = (float)acc + h_own;
}

__global__ __launch_bounds__(SBS, 1)
void probe_exch64(u64* ht, float* __restrict__ sink) {
    const int g = blockIdx.x;      // 64 WGs, 16 units each
    const int u0 = g * 16;
    const int tid = threadIdx.x;
    float h_own = (float)g;
    unsigned acc = 0;
    for (int t = 0; t < 2048; ++t) {
        __syncthreads();
        if (tid < 16) {
            h_own = fmaf(h_own, 0.5f, 1.f);
            __hip_atomic_store(ht + ((t + 1) & 1) * HDIM + u0 + tid,
                               pack_h((unsigned)(t + 1), h_own),
                               __ATOMIC_RELAXED, __HIP_MEMORY_SCOPE_AGENT);
        }
        const unsigned need = (unsigned)(t + 1);
        const u64* hp = ht + ((t + 1) & 1) * HDIM;
        u64 v0 = poll_h(hp + 2 * tid, need);
        u64 v1 = poll_h(hp + 2 * tid + 1, need);
        acc += (unsigned)v0 + (unsigned)v1;
        __syncthreads();
    }
    if (tid == 0) sink[256 + g] = (float)acc + h_own;
}

// probe_exch_xcd: 32 WGs on XCD0 (b&7==0), volatile L2-coherent exchange.
__global__ __launch_bounds__(SBS, 1)
void probe_exch_xcd(u64* hx, float* __restrict__ sink) {
    const int b = blockIdx.x;
    if (b & 7) return;               // keep only XCD-0 WGs (round-robin map)
    const int g = b >> 3;            // 0..31
    const int u0 = g * 8;            // 256 words total
    const int tid = threadIdx.x;
    float h_own = (float)g;
    unsigned acc = 0;
    for (int t = 0; t < TT; ++t) {
        __syncthreads();
        if (tid < 8) {
            h_own = fmaf(h_own, 0.5f, 1.f);
            *(volatile u64*)(hx + ((t + 1) & 1) * 256 + u0 + tid) =
                pack_h((unsigned)(t + 1), h_own);
        }
        if (tid < 256) {
            const unsigned need = (unsigned)(t + 1);
            volatile const u64* p = hx + ((t + 1) & 1) * 256 + tid;
            u64 v = *p;
            int it = 0;
            while ((unsigned)(v >> 32) < need && ++it < (1 << 17)) v = *p;
            acc += (unsigned)v + (unsigned)(it >= (1 << 17));
        }
        __syncthreads();
    }
    if (tid == 0) sink[320 + g] = (float)acc + h_own;
}

// ---------------- launch ----------------
extern "C" void kernel_launch(void* const* d_in, const int* in_sizes, int n_in,
                              void* d_out, int out_size, void* d_ws, size_t ws_size,
                              hipStream_t stream) {
    const int*   idx = (const int*)d_in[0];
    const float* emb = (const float*)d_in[1];
    const float* wih = (const float*)d_in[2];
    const float* whh = (const float*)d_in[3];
    const float* bih = (const float*)d_in[4];
    const float* bhh = (const float*)d_in[5];
    float* out = (float*)d_out;

    float* x    = (float*)d_ws;                 // [T,H]
    float* gi   = x   + (size_t)TT * HDIM;      // [T,3H]
    float* ys0  = gi  + (size_t)TT * 3 * HDIM;  // [T,H]
    char*  ctrl = (char*)(ys0 + (size_t)TT * HDIM);
    u64* h0t = (u64*)ctrl;                      // [2][H]
    u64* h1t = h0t + 2 * HDIM;                  // [2][H]
    unsigned* flags0 = (unsigned*)(h1t + 2 * HDIM);      // [2][L0WG*FSTR]
    u64* pe128 = (u64*)(flags0 + 2 * L0WG * FSTR);       // [2][H]
    u64* pe64  = pe128 + 2 * HDIM;                       // [2][H]
    u64* pex   = pe64 + 2 * HDIM;                        // [2][256]
    float* sink = (float*)(pex + 2 * 256);               // [512]
    size_t ctrl_bytes = (size_t)((char*)(sink + 512) - ctrl);

    hipMemsetAsync(ctrl, 0, ctrl_bytes, stream);

    embed_kernel<<<TT, 256, 0, stream>>>(idx, emb, x);

    const size_t wstride = (size_t)3 * HDIM * HDIM;
    const size_t bstride = (size_t)3 * HDIM;

    gemm_nt_bias<<<dim3(TT / BM, 3 * HDIM / BN), 256, 0, stream>>>(
        x, wih, bih, gi, TT, 3 * HDIM, HDIM);

    gru_pipe<<<L0WG + L1WG, SBS, 0, stream>>>(
        gi, whh, bhh,
        wih + wstride, whh + wstride, bih + bstride, bhh + bstride,
        ys0, out, h0t, h1t, flags0);

    // ---- diagnostic probes (scratch only) ----
    probe_compute<<<128, SBS, 0, stream>>>(whh, wih, x, sink);
    probe_exch128<<<128, SBS, 0, stream>>>(pe128, sink);
    probe_exch64<<<64, SBS, 0, stream>>>(pe64, sink);
    probe_exch_xcd<<<256, SBS, 0, stream>>>(pex, sink);
}

// Round 10
// 24273.773 us; speedup vs baseline: 1.6519x; 1.6519x over previous
//
#include <hip/hip_runtime.h>
#include <hip/hip_bf16.h>

// v10: hierarchical h-exchange.
// 256 WGs (1/CU). Per XCD (b&7): slot0 = aggregator (polls global tagged h at
// 8 pollers/word, re-stores into XCD-local L2 mirror via plain stores);
// slots 1-8 = layer0 WGs (16 units, whh bf16 in LDS, gi0 from GEMM);
// slots 9-24 = layer1 WGs (8 units, whh+wih bf16 in LDS, gi on the fly).
// Consumers poll mirror with sc0 (L2-hit) loads; sticky fallback to direct
// L3 polling on XCC-mismatch or timeout (correctness placement-independent).

#define TT    4096
#define HDIM  1024
#define L0WG  64
#define L1WG  128
#define SBS   512
#define FSTR  16
typedef unsigned short ushort_t;
typedef unsigned long long u64;

// ---------------- embedding gather ----------------
__global__ void embed_kernel(const int* __restrict__ idx,
                             const float* __restrict__ emb,
                             float* __restrict__ x) {
    int t = blockIdx.x;
    int row = idx[t];
    const float4* src = reinterpret_cast<const float4*>(emb + (size_t)row * HDIM);
    float4* dst = reinterpret_cast<float4*>(x + (size_t)t * HDIM);
    dst[threadIdx.x] = src[threadIdx.x];
}

// ---------------- fp32 NT GEMM (gi0 precompute) ----------------
#define BM 64
#define BN 64
#define BK 32
__global__ __launch_bounds__(256)
void gemm_nt_bias(const float* __restrict__ A,
                  const float* __restrict__ Bw,
                  const float* __restrict__ bias,
                  float* __restrict__ C,
                  int M, int N, int K) {
    __shared__ float As[BK][BM];
    __shared__ float Bs[BK][BN];
    const int tid = threadIdx.x;
    const int m0 = blockIdx.x * BM;
    const int n0 = blockIdx.y * BN;
    const int tx = tid & 15, ty = tid >> 4;
    const int lr = tid >> 3;
    const int lc = (tid & 7) * 4;
    float acc[4][4] = {};
    for (int k0 = 0; k0 < K; k0 += BK) {
#pragma unroll
        for (int pass = 0; pass < 2; ++pass) {
            int m = lr + pass * 32;
            float4 v = *reinterpret_cast<const float4*>(A + (size_t)(m0 + m) * K + k0 + lc);
            As[lc + 0][m] = v.x; As[lc + 1][m] = v.y;
            As[lc + 2][m] = v.z; As[lc + 3][m] = v.w;
            float4 u = *reinterpret_cast<const float4*>(Bw + (size_t)(n0 + m) * K + k0 + lc);
            Bs[lc + 0][m] = u.x; Bs[lc + 1][m] = u.y;
            Bs[lc + 2][m] = u.z; Bs[lc + 3][m] = u.w;
        }
        __syncthreads();
#pragma unroll
        for (int kk = 0; kk < BK; ++kk) {
            float4 a = *reinterpret_cast<const float4*>(&As[kk][ty * 4]);
            float4 b = *reinterpret_cast<const float4*>(&Bs[kk][tx * 4]);
            float av[4] = {a.x, a.y, a.z, a.w};
            float bv[4] = {b.x, b.y, b.z, b.w};
#pragma unroll
            for (int i = 0; i < 4; ++i)
#pragma unroll
                for (int j = 0; j < 4; ++j)
                    acc[i][j] = fmaf(av[i], bv[j], acc[i][j]);
        }
        __syncthreads();
    }
    float4 b4 = *reinterpret_cast<const float4*>(bias + n0 + tx * 4);
    float bb[4] = {b4.x, b4.y, b4.z, b4.w};
#pragma unroll
    for (int i = 0; i < 4; ++i) {
        int m = m0 + ty * 4 + i;
        float4 o;
        o.x = acc[i][0] + bb[0];
        o.y = acc[i][1] + bb[1];
        o.z = acc[i][2] + bb[2];
        o.w = acc[i][3] + bb[3];
        *reinterpret_cast<float4*>(C + (size_t)m * N + n0 + tx * 4) = o;
    }
}

// ---------------- helpers ----------------
__device__ __forceinline__ float fsig(float x) { return 1.f / (1.f + __expf(-x)); }
__device__ __forceinline__ float ftanh(float x) {
    return fmaf(-2.f, 1.f / (1.f + __expf(2.f * x)), 1.f);
}
__device__ __forceinline__ float bflo(unsigned u) { return __uint_as_float(u << 16); }
__device__ __forceinline__ float bfhi(unsigned u) { return __uint_as_float(u & 0xffff0000u); }
__device__ __forceinline__ ushort_t f2bf(float f) {
    unsigned u = __float_as_uint(f);
    return (ushort_t)((u + 0x7FFFu + ((u >> 16) & 1u)) >> 16);
}
__device__ __forceinline__ u64 pack_h(unsigned seq, float h) {
    return ((u64)seq << 32) | (u64)__float_as_uint(h);
}
__device__ __forceinline__ u64 poll_h(const u64* p, unsigned need) {
    u64 v = __hip_atomic_load(p, __ATOMIC_RELAXED, __HIP_MEMORY_SCOPE_AGENT);
    while ((unsigned)(v >> 32) < need)
        v = __hip_atomic_load(p, __ATOMIC_RELAXED, __HIP_MEMORY_SCOPE_AGENT);
    return v;
}
__device__ __forceinline__ u64 load_l2(const u64* p) {
    u64 a = (u64)p, v;
    asm volatile("global_load_dwordx2 %0, %1, off sc0\n\t"
                 "s_waitcnt vmcnt(0)"
                 : "=v"(v) : "v"(a) : "memory");
    return v;
}
__device__ __forceinline__ void store_l2(u64* p, u64 v) {
    u64 a = (u64)p;
    asm volatile("global_store_dwordx2 %0, %1, off"
                 :: "v"(a), "v"(v) : "memory");
}
__device__ __forceinline__ unsigned xcc_id() {
    unsigned x;
    asm volatile("s_getreg_b32 %0, hwreg(20, 0, 8)" : "=s"(x));
    return x & 7u;
}
__device__ __forceinline__ u64 poll_mirror(const u64* mp, const u64* gp,
                                           unsigned need, int* to) {
    for (int i = 0; i < (1 << 13); ++i) {
        u64 v = load_l2(mp);
        if ((unsigned)(v >> 32) >= need) return v;
    }
    *to = 1;
    return poll_h(gp, need);
}
__device__ __forceinline__ float dot_bf16(uint2 w0, uint2 w1, uint2 w2, uint2 w3,
                                          float4 hA, float4 hB, float4 hC, float4 hD) {
    float p = 0.f;
    p = fmaf(bflo(w0.x), hA.x, p); p = fmaf(bfhi(w0.x), hA.y, p);
    p = fmaf(bflo(w0.y), hA.z, p); p = fmaf(bfhi(w0.y), hA.w, p);
    p = fmaf(bflo(w1.x), hB.x, p); p = fmaf(bfhi(w1.x), hB.y, p);
    p = fmaf(bflo(w1.y), hB.z, p); p = fmaf(bfhi(w1.y), hB.w, p);
    p = fmaf(bflo(w2.x), hC.x, p); p = fmaf(bfhi(w2.x), hC.y, p);
    p = fmaf(bflo(w2.y), hC.z, p); p = fmaf(bfhi(w2.y), hC.w, p);
    p = fmaf(bflo(w3.x), hD.x, p); p = fmaf(bfhi(w3.x), hD.y, p);
    p = fmaf(bflo(w3.y), hD.z, p); p = fmaf(bfhi(w3.y), hD.w, p);
    return p;
}

// ---------------- fused hierarchical scan ----------------
__global__ __launch_bounds__(SBS, 1)
void gru_hier(const float* __restrict__ gi0,
              const float* __restrict__ whh0,
              const float* __restrict__ bhh0,
              const float* __restrict__ wih1,
              const float* __restrict__ whh1,
              const float* __restrict__ bih1,
              const float* __restrict__ bhh1,
              float* ys0,
              float* __restrict__ out,
              u64* h0t, u64* h1t,
              u64* mir,            // [8][2][2][HDIM] tagged
              unsigned* hdr,       // [8][2]
              unsigned* flags0) {  // [2][L0WG*FSTR]
    const int b    = blockIdx.x;
    const int xcd  = b & 7;
    const int slot = b >> 3;
    const int tid  = threadIdx.x;
    const int wv   = tid >> 6;
    const int ln   = tid & 63;

    __shared__ __align__(16) u64 smem8[13864];   // 110912 B
    __shared__ int s_mode;
    char* base = (char*)smem8;

    // ================= aggregator (slot 0, one per XCD) =================
    if (slot == 0) {
        if (tid == 0) {
            unsigned hv = 0x100u | xcc_id();
            __hip_atomic_store(hdr + xcd * 2 + 0, hv, __ATOMIC_RELAXED, __HIP_MEMORY_SCOPE_AGENT);
            __hip_atomic_store(hdr + xcd * 2 + 1, hv, __ATOMIC_RELAXED, __HIP_MEMORY_SCOPE_AGENT);
        }
        const int half = wv >> 2;                      // waves 0-3: h0, 4-7: h1
        const u64* src = half ? h1t : h0t;
        u64* dst = mir + (size_t)(xcd * 2 + half) * 2 * HDIM;
        const int q = tid & 255;
        for (int t = 1; t <= TT; ++t) {
            const int par = t & 1;
            const u64* s = src + (size_t)par * HDIM;
            u64* d = dst + (size_t)par * HDIM;
#pragma unroll
            for (int k = 0; k < 4; ++k) {
                u64 v = poll_h(s + k * 256 + q, (unsigned)t);
                store_l2(d + k * 256 + q, v);
            }
        }
        return;
    }
    if (slot > 24) return;

    if (slot <= 8) {
        // ================= layer 0 (16 units/WG) =================
        const int g = (slot - 1) * 8 + xcd;            // 0..63
        const int u0 = g * 16;
        ushort_t* lwh = (ushort_t*)base;               // 48 rows x 1024 bf16
        float* lhf = (float*)(base + 98304);
        float* lgh = (float*)(base + 102400);          // 48

        for (int i = tid; i < 48 * 512; i += SBS) {
            const int r = i >> 9, c = i & 511;
            const size_t grow = (size_t)((r >> 4) * HDIM + u0 + (r & 15)) * HDIM;
            const float2 a = *reinterpret_cast<const float2*>(whh0 + grow + 2 * c);
            reinterpret_cast<unsigned*>(lwh)[r * 512 + c] =
                (unsigned)f2bf(a.x) | ((unsigned)f2bf(a.y) << 16);
        }
        reinterpret_cast<float2*>(lhf)[tid] = float2{0.f, 0.f};

        float bhr = 0.f, bhz = 0.f, bhn = 0.f;
        float gir = 0.f, giz = 0.f, gin = 0.f, h_own = 0.f;
        if (tid < 16) {
            const int u = u0 + tid;
            bhr = bhh0[u]; bhz = bhh0[HDIM + u]; bhn = bhh0[2 * HDIM + u];
            gir = gi0[u];  giz = gi0[HDIM + u];  gin = gi0[2 * HDIM + u];
        }
        if (tid == 0) {
            unsigned hv;
            while ((hv = __hip_atomic_load(hdr + xcd * 2, __ATOMIC_RELAXED,
                                           __HIP_MEMORY_SCOPE_AGENT)) == 0u)
                __builtin_amdgcn_s_sleep(2);
            s_mode = ((hv & 0xffu) == xcc_id()) ? 1 : 0;
        }
        __syncthreads();

        const u64* mirT = mir + (size_t)(xcd * 2 + 0) * 2 * HDIM;

        for (int t = 0; t < TT; ++t) {
            float nir = 0.f, niz = 0.f, nin = 0.f;
            if (tid < 16 && t + 1 < TT) {
                const float* p = gi0 + (size_t)(t + 1) * 3 * HDIM + u0 + tid;
                nir = p[0]; niz = p[HDIM]; nin = p[2 * HDIM];
            }
            if (wv < 6) {
                const float4* lh4 = reinterpret_cast<const float4*>(lhf);
                float4 hA = lh4[ln], hB = lh4[64 + ln], hC = lh4[128 + ln], hD = lh4[192 + ln];
                const uint2* wh2 = reinterpret_cast<const uint2*>(lwh);
#pragma unroll
                for (int rr = 0; rr < 8; ++rr) {
                    const int row = wv * 8 + rr;
                    const uint2* wr = wh2 + row * 256;
                    float p = dot_bf16(wr[ln], wr[64 + ln], wr[128 + ln], wr[192 + ln],
                                       hA, hB, hC, hD);
                    p += __shfl_xor(p, 1);  p += __shfl_xor(p, 2);
                    p += __shfl_xor(p, 4);  p += __shfl_xor(p, 8);
                    p += __shfl_xor(p, 16); p += __shfl_xor(p, 32);
                    if (ln == 0) lgh[row] = p;
                }
            }
            __syncthreads();   // S1

            if (tid < 16) {
                const int u = u0 + tid;
                const float r = fsig(gir + lgh[tid] + bhr);
                const float z = fsig(giz + lgh[16 + tid] + bhz);
                const float n = ftanh(gin + r * (lgh[32 + tid] + bhn));
                const float h_new = (1.f - z) * n + z * h_own;
                h_own = h_new;
                __hip_atomic_store(h0t + ((t + 1) & 1) * HDIM + u,
                                   pack_h((unsigned)(t + 1), h_new),
                                   __ATOMIC_RELAXED, __HIP_MEMORY_SCOPE_AGENT);
                __hip_atomic_store(ys0 + (size_t)t * HDIM + u, h_new,
                                   __ATOMIC_RELAXED, __HIP_MEMORY_SCOPE_AGENT);
                if (t == TT - 1) out[(size_t)TT * HDIM + u] = h_new;
            }
            if (tid == 0) {
                __threadfence();
                __hip_atomic_store(flags0 + (t & 1) * (L0WG * FSTR) + g * FSTR,
                                   (unsigned)(t + 1),
                                   __ATOMIC_RELAXED, __HIP_MEMORY_SCOPE_AGENT);
            }
            if (t + 1 < TT) {
                const unsigned need = (unsigned)(t + 1);
                const u64* gp = h0t + ((t + 1) & 1) * HDIM;
                const u64* mp = mirT + (size_t)((t + 1) & 1) * HDIM;
                u64 v0, v1;
                if (s_mode) {
                    int to = 0;
                    v0 = poll_mirror(mp + 2 * tid,     gp + 2 * tid,     need, &to);
                    v1 = poll_mirror(mp + 2 * tid + 1, gp + 2 * tid + 1, need, &to);
                    if (to) s_mode = 0;
                } else {
                    v0 = poll_h(gp + 2 * tid, need);
                    v1 = poll_h(gp + 2 * tid + 1, need);
                }
                float2 hv2;
                hv2.x = __uint_as_float((unsigned)v0);
                hv2.y = __uint_as_float((unsigned)v1);
                reinterpret_cast<float2*>(lhf)[tid] = hv2;
            }
            gir = nir; giz = niz; gin = nin;
            __syncthreads();   // S2
        }
        return;
    }

    // ================= layer 1 (8 units/WG) =================
    {
        const int g1 = (slot - 9) * 8 + xcd;           // 0..127
        const int u0 = g1 * 8;
        ushort_t* lwh = (ushort_t*)base;               // 24 rows whh
        ushort_t* lwi = (ushort_t*)(base + 49152);     // 24 rows wih
        float* lhf = (float*)(base + 98304);
        float* ly0 = (float*)(base + 102400);
        float* ly1 = (float*)(base + 106496);
        float* lgi = (float*)(base + 110592);          // [2][24]
        float* lgh = (float*)(base + 110784);          // 24

        for (int i = tid; i < 24 * 512; i += SBS) {
            const int r = i >> 9, c = i & 511;
            const size_t grow = (size_t)((r >> 3) * HDIM + u0 + (r & 7)) * HDIM;
            const float2 a = *reinterpret_cast<const float2*>(whh1 + grow + 2 * c);
            reinterpret_cast<unsigned*>(lwh)[r * 512 + c] =
                (unsigned)f2bf(a.x) | ((unsigned)f2bf(a.y) << 16);
            const float2 w = *reinterpret_cast<const float2*>(wih1 + grow + 2 * c);
            reinterpret_cast<unsigned*>(lwi)[r * 512 + c] =
                (unsigned)f2bf(w.x) | ((unsigned)f2bf(w.y) << 16);
        }
        reinterpret_cast<float2*>(lhf)[tid] = float2{0.f, 0.f};

        float bir = 0.f, biz = 0.f, bin = 0.f;
        float bhr = 0.f, bhz = 0.f, bhn = 0.f, h_own = 0.f;
        if (tid < 8) {
            const int u = u0 + tid;
            bir = bih1[u]; biz = bih1[HDIM + u]; bin = bih1[2 * HDIM + u];
            bhr = bhh1[u]; bhz = bhh1[HDIM + u]; bhn = bhh1[2 * HDIM + u];
        }
        if (tid == 0) {
            unsigned hv;
            while ((hv = __hip_atomic_load(hdr + xcd * 2 + 1, __ATOMIC_RELAXED,
                                           __HIP_MEMORY_SCOPE_AGENT)) == 0u)
                __builtin_amdgcn_s_sleep(2);
            s_mode = ((hv & 0xffu) == xcc_id()) ? 1 : 0;
        }
        // stage y(0)
        if (wv == 6) {
            const unsigned* f = flags0 + 0 * (L0WG * FSTR) + ln * FSTR;
            while (__hip_atomic_load(f, __ATOMIC_RELAXED, __HIP_MEMORY_SCOPE_AGENT) < 1u)
                __builtin_amdgcn_s_sleep(1);
            const u64* s8 = reinterpret_cast<const u64*>(ys0);
            u64* d8 = reinterpret_cast<u64*>(ly0);
#pragma unroll
            for (int k = 0; k < 8; ++k)
                d8[k * 64 + ln] = __hip_atomic_load(s8 + k * 64 + ln, __ATOMIC_RELAXED,
                                                    __HIP_MEMORY_SCOPE_AGENT);
        }
        __syncthreads();

        // gi(0) (waves 3-5) ; stage y(1) (wave 6)
        if (wv >= 3 && wv < 6) {
            const float4* ly4 = reinterpret_cast<const float4*>(ly0);
            float4 yA = ly4[ln], yB = ly4[64 + ln], yC = ly4[128 + ln], yD = ly4[192 + ln];
            const uint2* wi2 = reinterpret_cast<const uint2*>(lwi);
#pragma unroll
            for (int rr = 0; rr < 8; ++rr) {
                const int row = (wv - 3) * 8 + rr;
                const uint2* wr = wi2 + row * 256;
                float p = dot_bf16(wr[ln], wr[64 + ln], wr[128 + ln], wr[192 + ln],
                                   yA, yB, yC, yD);
                p += __shfl_xor(p, 1);  p += __shfl_xor(p, 2);
                p += __shfl_xor(p, 4);  p += __shfl_xor(p, 8);
                p += __shfl_xor(p, 16); p += __shfl_xor(p, 32);
                if (ln == 0) lgi[row] = p;
            }
        }
        if (wv == 6 && TT > 1) {
            const unsigned* f = flags0 + 1 * (L0WG * FSTR) + ln * FSTR;
            while (__hip_atomic_load(f, __ATOMIC_RELAXED, __HIP_MEMORY_SCOPE_AGENT) < 2u)
                __builtin_amdgcn_s_sleep(1);
            const u64* s8 = reinterpret_cast<const u64*>(ys0 + HDIM);
            u64* d8 = reinterpret_cast<u64*>(ly1);
#pragma unroll
            for (int k = 0; k < 8; ++k)
                d8[k * 64 + ln] = __hip_atomic_load(s8 + k * 64 + ln, __ATOMIC_RELAXED,
                                                    __HIP_MEMORY_SCOPE_AGENT);
        }
        __syncthreads();

        const u64* mirT = mir + (size_t)(xcd * 2 + 1) * 2 * HDIM;

        for (int t = 0; t < TT; ++t) {
            if (wv < 3) {              // gh = whh . h(t)
                const float4* lh4 = reinterpret_cast<const float4*>(lhf);
                float4 hA = lh4[ln], hB = lh4[64 + ln], hC = lh4[128 + ln], hD = lh4[192 + ln];
                const uint2* wh2 = reinterpret_cast<const uint2*>(lwh);
#pragma unroll
                for (int rr = 0; rr < 8; ++rr) {
                    const int row = wv * 8 + rr;
                    const uint2* wr = wh2 + row * 256;
                    float p = dot_bf16(wr[ln], wr[64 + ln], wr[128 + ln], wr[192 + ln],
                                       hA, hB, hC, hD);
                    p += __shfl_xor(p, 1);  p += __shfl_xor(p, 2);
                    p += __shfl_xor(p, 4);  p += __shfl_xor(p, 8);
                    p += __shfl_xor(p, 16); p += __shfl_xor(p, 32);
                    if (ln == 0) lgh[row] = p;
                }
            } else if (wv < 6) {       // gi(t+1) = wih . y(t+1)
                const float* lys = ((t + 1) & 1) ? ly1 : ly0;
                const float4* ly4 = reinterpret_cast<const float4*>(lys);
                float4 yA = ly4[ln], yB = ly4[64 + ln], yC = ly4[128 + ln], yD = ly4[192 + ln];
                const uint2* wi2 = reinterpret_cast<const uint2*>(lwi);
#pragma unroll
                for (int rr = 0; rr < 8; ++rr) {
                    const int row = (wv - 3) * 8 + rr;
                    const uint2* wr = wi2 + row * 256;
                    float p = dot_bf16(wr[ln], wr[64 + ln], wr[128 + ln], wr[192 + ln],
                                       yA, yB, yC, yD);
                    p += __shfl_xor(p, 1);  p += __shfl_xor(p, 2);
                    p += __shfl_xor(p, 4);  p += __shfl_xor(p, 8);
                    p += __shfl_xor(p, 16); p += __shfl_xor(p, 32);
                    if (ln == 0) lgi[((t + 1) & 1) * 24 + row] = p;
                }
            } else if (wv == 6) {      // stage y(t+2)
                const int s = t + 2;
                if (s < TT) {
                    const unsigned* f = flags0 + (s & 1) * (L0WG * FSTR) + ln * FSTR;
                    const unsigned need = (unsigned)(s + 1);
                    while (__hip_atomic_load(f, __ATOMIC_RELAXED, __HIP_MEMORY_SCOPE_AGENT) < need) {}
                    const u64* s8 = reinterpret_cast<const u64*>(ys0 + (size_t)s * HDIM);
                    u64* d8 = reinterpret_cast<u64*>((t & 1) ? ly1 : ly0);
#pragma unroll
                    for (int k = 0; k < 8; ++k)
                        d8[k * 64 + ln] = __hip_atomic_load(s8 + k * 64 + ln, __ATOMIC_RELAXED,
                                                            __HIP_MEMORY_SCOPE_AGENT);
                }
            }
            __syncthreads();   // S1

            if (tid < 8) {
                const int u = u0 + tid;
                const float r = fsig(lgi[(t & 1) * 24 + tid] + bir + lgh[tid] + bhr);
                const float z = fsig(lgi[(t & 1) * 24 + 8 + tid] + biz + lgh[8 + tid] + bhz);
                const float n = ftanh(lgi[(t & 1) * 24 + 16 + tid] + bin
                                      + r * (lgh[16 + tid] + bhn));
                const float h_new = (1.f - z) * n + z * h_own;
                h_own = h_new;
                __hip_atomic_store(h1t + ((t + 1) & 1) * HDIM + u,
                                   pack_h((unsigned)(t + 1), h_new),
                                   __ATOMIC_RELAXED, __HIP_MEMORY_SCOPE_AGENT);
                out[(size_t)t * HDIM + u] = h_new;
                if (t == TT - 1) out[(size_t)TT * HDIM + HDIM + u] = h_new;
            }
            if (t + 1 < TT) {
                const unsigned need = (unsigned)(t + 1);
                const u64* gp = h1t + ((t + 1) & 1) * HDIM;
                const u64* mp = mirT + (size_t)((t + 1) & 1) * HDIM;
                u64 v0, v1;
                if (s_mode) {
                    int to = 0;
                    v0 = poll_mirror(mp + 2 * tid,     gp + 2 * tid,     need, &to);
                    v1 = poll_mirror(mp + 2 * tid + 1, gp + 2 * tid + 1, need, &to);
                    if (to) s_mode = 0;
                } else {
                    v0 = poll_h(gp + 2 * tid, need);
                    v1 = poll_h(gp + 2 * tid + 1, need);
                }
                float2 hv2;
                hv2.x = __uint_as_float((unsigned)v0);
                hv2.y = __uint_as_float((unsigned)v1);
                reinterpret_cast<float2*>(lhf)[tid] = hv2;
            }
            __syncthreads();   // S2
        }
    }
}

// ---------------- launch ----------------
extern "C" void kernel_launch(void* const* d_in, const int* in_sizes, int n_in,
                              void* d_out, int out_size, void* d_ws, size_t ws_size,
                              hipStream_t stream) {
    const int*   idx = (const int*)d_in[0];
    const float* emb = (const float*)d_in[1];
    const float* wih = (const float*)d_in[2];
    const float* whh = (const float*)d_in[3];
    const float* bih = (const float*)d_in[4];
    const float* bhh = (const float*)d_in[5];
    float* out = (float*)d_out;

    float* x    = (float*)d_ws;                 // [T,H]
    float* gi0  = x   + (size_t)TT * HDIM;      // [T,3H]
    float* ys0  = gi0 + (size_t)TT * 3 * HDIM;  // [T,H]
    char*  ctrl = (char*)(ys0 + (size_t)TT * HDIM);
    u64* h0t = (u64*)ctrl;                      // [2][H]
    u64* h1t = h0t + 2 * HDIM;                  // [2][H]
    u64* mir = h1t + 2 * HDIM;                  // [8][2][2][H]
    unsigned* hdr = (unsigned*)(mir + (size_t)8 * 2 * 2 * HDIM);   // [8][2]
    unsigned* flags0 = hdr + 16;                // [2][L0WG*FSTR]
    size_t ctrl_bytes = (size_t)((char*)(flags0 + 2 * L0WG * FSTR) - ctrl);

    hipMemsetAsync(ctrl, 0, ctrl_bytes, stream);

    embed_kernel<<<TT, 256, 0, stream>>>(idx, emb, x);

    const size_t wstride = (size_t)3 * HDIM * HDIM;
    const size_t bstride = (size_t)3 * HDIM;

    gemm_nt_bias<<<dim3(TT / BM, 3 * HDIM / BN), 256, 0, stream>>>(
        x, wih, bih, gi0, TT, 3 * HDIM, HDIM);

    gru_hier<<<256, SBS, 0, stream>>>(
        gi0, whh, bhh,
        wih + wstride, whh + wstride, bih + bstride, bhh + bstride,
        ys0, out, h0t, h1t, mir, hdr, flags0);
}

// Round 11
// 15942.303 us; speedup vs baseline: 2.5152x; 1.5226x over previous
//
#include <hip/hip_runtime.h>
#include <hip/hip_bf16.h>

// v11 = v5 (best baseline, 16.9ms) with ONE change: replicated tagged
// h-exchange. Producers store packed (seq|h) to 8 replica arrays (one per
// XCD); consumers poll replica[blockIdx&7]. Pollers-per-L3-line drops 8x.
// No aggregator hop (v10's serial-detect mistake). Ring-2 safety per replica.

#define TT    4096
#define HDIM  1024
#define L0WG  64
#define L1WG  128
#define SBS   512
#define FSTR  16
#define NREP  8
typedef unsigned long long u64;

// ---------------- embedding gather ----------------
__global__ void embed_kernel(const int* __restrict__ idx,
                             const float* __restrict__ emb,
                             float* __restrict__ x) {
    int t = blockIdx.x;
    int row = idx[t];
    const float4* src = reinterpret_cast<const float4*>(emb + (size_t)row * HDIM);
    float4* dst = reinterpret_cast<float4*>(x + (size_t)t * HDIM);
    dst[threadIdx.x] = src[threadIdx.x];
}

// ---------------- fp32 NT GEMM ----------------
#define BM 64
#define BN 64
#define BK 32
__global__ __launch_bounds__(256)
void gemm_nt_bias(const float* __restrict__ A,
                  const float* __restrict__ Bw,
                  const float* __restrict__ bias,
                  float* __restrict__ C,
                  int M, int N, int K) {
    __shared__ float As[BK][BM];
    __shared__ float Bs[BK][BN];
    const int tid = threadIdx.x;
    const int m0 = blockIdx.x * BM;
    const int n0 = blockIdx.y * BN;
    const int tx = tid & 15, ty = tid >> 4;
    const int lr = tid >> 3;
    const int lc = (tid & 7) * 4;

    float acc[4][4] = {};

    for (int k0 = 0; k0 < K; k0 += BK) {
#pragma unroll
        for (int pass = 0; pass < 2; ++pass) {
            int m = lr + pass * 32;
            float4 v = *reinterpret_cast<const float4*>(A + (size_t)(m0 + m) * K + k0 + lc);
            As[lc + 0][m] = v.x; As[lc + 1][m] = v.y;
            As[lc + 2][m] = v.z; As[lc + 3][m] = v.w;
            float4 u = *reinterpret_cast<const float4*>(Bw + (size_t)(n0 + m) * K + k0 + lc);
            Bs[lc + 0][m] = u.x; Bs[lc + 1][m] = u.y;
            Bs[lc + 2][m] = u.z; Bs[lc + 3][m] = u.w;
        }
        __syncthreads();
#pragma unroll
        for (int kk = 0; kk < BK; ++kk) {
            float4 a = *reinterpret_cast<const float4*>(&As[kk][ty * 4]);
            float4 b = *reinterpret_cast<const float4*>(&Bs[kk][tx * 4]);
            float av[4] = {a.x, a.y, a.z, a.w};
            float bv[4] = {b.x, b.y, b.z, b.w};
#pragma unroll
            for (int i = 0; i < 4; ++i)
#pragma unroll
                for (int j = 0; j < 4; ++j)
                    acc[i][j] = fmaf(av[i], bv[j], acc[i][j]);
        }
        __syncthreads();
    }

    float4 b4 = *reinterpret_cast<const float4*>(bias + n0 + tx * 4);
    float bb[4] = {b4.x, b4.y, b4.z, b4.w};
#pragma unroll
    for (int i = 0; i < 4; ++i) {
        int m = m0 + ty * 4 + i;
        float4 o;
        o.x = acc[i][0] + bb[0];
        o.y = acc[i][1] + bb[1];
        o.z = acc[i][2] + bb[2];
        o.w = acc[i][3] + bb[3];
        *reinterpret_cast<float4*>(C + (size_t)m * N + n0 + tx * 4) = o;
    }
}

// ---------------- helpers ----------------
__device__ __forceinline__ float dot4(float4 a, float4 b) {
    return fmaf(a.x, b.x, fmaf(a.y, b.y, fmaf(a.z, b.z, a.w * b.w)));
}
__device__ __forceinline__ float fsig(float x) { return 1.f / (1.f + __expf(-x)); }
__device__ __forceinline__ float ftanh(float x) {
    return fmaf(-2.f, 1.f / (1.f + __expf(2.f * x)), 1.f);
}
__device__ __forceinline__ u64 pack_h(unsigned seq, float h) {
    return ((u64)seq << 32) | (u64)__float_as_uint(h);
}
__device__ __forceinline__ u64 poll_h(const u64* p, unsigned need) {
    u64 v = __hip_atomic_load(p, __ATOMIC_RELAXED, __HIP_MEMORY_SCOPE_AGENT);
    while ((unsigned)(v >> 32) < need)
        v = __hip_atomic_load(p, __ATOMIC_RELAXED, __HIP_MEMORY_SCOPE_AGENT);
    return v;
}
// publish one packed word to all NREP replicas ([NREP][2][HDIM] layout)
__device__ __forceinline__ void pub_h(u64* rep, int par, int idx, u64 v) {
#pragma unroll
    for (int r = 0; r < NREP; ++r)
        __hip_atomic_store(rep + ((size_t)r * 2 + par) * HDIM + idx, v,
                           __ATOMIC_RELAXED, __HIP_MEMORY_SCOPE_AGENT);
}

// ---------------- fused pipelined scan v11 ----------------
__global__ __launch_bounds__(SBS, 1)
void gru_pipe(const float* __restrict__ gi0,
              const float* __restrict__ whh0,
              const float* __restrict__ bhh0,
              const float* __restrict__ wih1,
              const float* __restrict__ whh1,
              const float* __restrict__ bih1,
              const float* __restrict__ bhh1,
              float* ys0,
              float* __restrict__ out,
              u64* h0rep, u64* h1rep,     // [NREP][2][HDIM] tagged
              unsigned* flags0) {          // [2][L0WG*FSTR]
    const int tid  = threadIdx.x;
    const int slot = tid >> 3;
    const int l8   = tid & 7;
    const int xcd  = blockIdx.x & 7;

    __shared__ float lds_h[HDIM];
    __shared__ float lds_y[HDIM];
    __shared__ float lds_gh[48];

    if (blockIdx.x < L0WG) {
        // ================= layer 0 =================
        const int g = blockIdx.x;

        float4 Wlo[16], Whi[16];
        if (slot < 48) {
            const int q = slot >> 4, jl = slot & 15;
            const float4* row4 = reinterpret_cast<const float4*>(
                whh0 + (size_t)(q * HDIM + g * 16 + jl) * HDIM);
#pragma unroll
            for (int k4 = 0; k4 < 16; ++k4) Wlo[k4] = row4[k4 * 8 + l8];
#pragma unroll
            for (int k4 = 0; k4 < 16; ++k4) Whi[k4] = row4[(k4 + 16) * 8 + l8];
        } else {
#pragma unroll
            for (int k4 = 0; k4 < 16; ++k4) { Wlo[k4] = float4{0,0,0,0}; Whi[k4] = float4{0,0,0,0}; }
        }

        float bh0 = 0.f, bh1 = 0.f, bh2 = 0.f;
        float gir = 0.f, giz = 0.f, gin = 0.f;
        float h_own = 0.f;
        if (tid < 16) {
            const int gj = g * 16 + tid;
            bh0 = bhh0[0 * HDIM + gj];
            bh1 = bhh0[1 * HDIM + gj];
            bh2 = bhh0[2 * HDIM + gj];
            gir = gi0[gj];
            giz = gi0[HDIM + gj];
            gin = gi0[2 * HDIM + gj];
        }

        lds_h[tid] = 0.f;
        lds_h[tid + SBS] = 0.f;
        __syncthreads();

        const float4* lh4 = reinterpret_cast<const float4*>(lds_h);

        for (int t = 0; t < TT; ++t) {
            float nir = 0.f, niz = 0.f, nin = 0.f;
            if (tid < 16 && t + 1 < TT) {
                const float* base = gi0 + (size_t)(t + 1) * 3 * HDIM + g * 16 + tid;
                nir = base[0];
                niz = base[HDIM];
                nin = base[2 * HDIM];
            }

            if (slot < 48) {
                float p0 = 0.f, p1 = 0.f;
#pragma unroll
                for (int k4 = 0; k4 < 16; ++k4) p0 += dot4(Wlo[k4], lh4[k4 * 8 + l8]);
#pragma unroll
                for (int k4 = 0; k4 < 16; ++k4) p1 += dot4(Whi[k4], lh4[(k4 + 16) * 8 + l8]);
                float p = p0 + p1;
                p += __shfl_xor(p, 1);
                p += __shfl_xor(p, 2);
                p += __shfl_xor(p, 4);
                if (l8 == 0) lds_gh[slot] = p;
            }
            __syncthreads();

            if (tid < 16) {
                const int gj = g * 16 + tid;
                const float hr = lds_gh[tid]      + bh0;
                const float hz = lds_gh[16 + tid] + bh1;
                const float hn = lds_gh[32 + tid] + bh2;
                const float r = fsig(gir + hr);
                const float z = fsig(giz + hz);
                const float n = ftanh(gin + r * hn);
                const float h_new = (1.f - z) * n + z * h_own;
                h_own = h_new;
                pub_h(h0rep, (t + 1) & 1, gj, pack_h((unsigned)(t + 1), h_new));
                __hip_atomic_store(ys0 + (size_t)t * HDIM + gj, h_new,
                                   __ATOMIC_RELAXED, __HIP_MEMORY_SCOPE_AGENT);
                if (t == TT - 1) out[(size_t)TT * HDIM + gj] = h_new;
            }
            if (tid == 0) {
                __threadfence();
                __hip_atomic_store(flags0 + (t & 1) * (L0WG * FSTR) + g * FSTR,
                                   (unsigned)(t + 1),
                                   __ATOMIC_RELAXED, __HIP_MEMORY_SCOPE_AGENT);
            }

            {
                const unsigned need = (unsigned)(t + 1);
                const u64* hp = h0rep + ((size_t)xcd * 2 + ((t + 1) & 1)) * HDIM;
                u64 v0 = poll_h(hp + 2 * tid, need);
                u64 v1 = poll_h(hp + 2 * tid + 1, need);
                float2 hv;
                hv.x = __uint_as_float((unsigned)v0);
                hv.y = __uint_as_float((unsigned)v1);
                reinterpret_cast<float2*>(lds_h)[tid] = hv;
            }
            gir = nir; giz = niz; gin = nin;
            __syncthreads();
        }
    } else {
        // ================= layer 1 =================
        const int g1 = blockIdx.x - L0WG;

        float4 Wlo[16], Whi[16];
        if (slot < 48) {
            const int ss = (slot < 24) ? slot : slot - 24;
            const int q = ss >> 3, jl = ss & 7;
            const float* mat = (slot < 24) ? whh1 : wih1;
            const float4* row4 = reinterpret_cast<const float4*>(
                mat + (size_t)(q * HDIM + g1 * 8 + jl) * HDIM);
#pragma unroll
            for (int k4 = 0; k4 < 16; ++k4) Wlo[k4] = row4[k4 * 8 + l8];
#pragma unroll
            for (int k4 = 0; k4 < 16; ++k4) Whi[k4] = row4[(k4 + 16) * 8 + l8];
        } else {
#pragma unroll
            for (int k4 = 0; k4 < 16; ++k4) { Wlo[k4] = float4{0,0,0,0}; Whi[k4] = float4{0,0,0,0}; }
        }

        float bh0 = 0.f, bh1 = 0.f, bh2 = 0.f;
        float bi0 = 0.f, bi1 = 0.f, bi2 = 0.f;
        float h_own = 0.f;
        if (tid < 8) {
            const int u = g1 * 8 + tid;
            bh0 = bhh1[0 * HDIM + u];
            bh1 = bhh1[1 * HDIM + u];
            bh2 = bhh1[2 * HDIM + u];
            bi0 = bih1[0 * HDIM + u];
            bi1 = bih1[1 * HDIM + u];
            bi2 = bih1[2 * HDIM + u];
        }

        lds_h[tid] = 0.f;
        lds_h[tid + SBS] = 0.f;
        if (tid >= 448) {
            const int l = tid - 448;
            const unsigned* f = flags0 + 0 * (L0WG * FSTR) + l * FSTR;
            while (__hip_atomic_load(f, __ATOMIC_RELAXED, __HIP_MEMORY_SCOPE_AGENT) < 1u)
                __builtin_amdgcn_s_sleep(1);
            const u64* ysrc = reinterpret_cast<const u64*>(ys0);
#pragma unroll
            for (int k = 0; k < 8; ++k) {
                u64 yv = __hip_atomic_load(ysrc + l * 8 + k, __ATOMIC_RELAXED,
                                           __HIP_MEMORY_SCOPE_AGENT);
                float2 yf;
                yf.x = __uint_as_float((unsigned)yv);
                yf.y = __uint_as_float((unsigned)(yv >> 32));
                reinterpret_cast<float2*>(lds_y)[l * 8 + k] = yf;
            }
        }
        __syncthreads();

        const float4* lh4 = reinterpret_cast<const float4*>(lds_h);
        const float4* ly4 = reinterpret_cast<const float4*>(lds_y);

        for (int t = 0; t < TT; ++t) {
            if (slot < 48) {
                const float4* s4 = (slot < 24) ? lh4 : ly4;
                float p0 = 0.f, p1 = 0.f;
#pragma unroll
                for (int k4 = 0; k4 < 16; ++k4) p0 += dot4(Wlo[k4], s4[k4 * 8 + l8]);
#pragma unroll
                for (int k4 = 0; k4 < 16; ++k4) p1 += dot4(Whi[k4], s4[(k4 + 16) * 8 + l8]);
                float p = p0 + p1;
                p += __shfl_xor(p, 1);
                p += __shfl_xor(p, 2);
                p += __shfl_xor(p, 4);
                if (l8 == 0) lds_gh[slot] = p;
            }
            __syncthreads();

            if (tid < 8) {
                const int u = g1 * 8 + tid;
                const float hr = lds_gh[tid]      + bh0;
                const float hz = lds_gh[8 + tid]  + bh1;
                const float hn = lds_gh[16 + tid] + bh2;
                const float ir = lds_gh[24 + tid] + bi0;
                const float iz = lds_gh[32 + tid] + bi1;
                const float in_ = lds_gh[40 + tid] + bi2;
                const float r = fsig(ir + hr);
                const float z = fsig(iz + hz);
                const float n = ftanh(in_ + r * hn);
                const float h_new = (1.f - z) * n + z * h_own;
                h_own = h_new;
                pub_h(h1rep, (t + 1) & 1, u, pack_h((unsigned)(t + 1), h_new));
                out[(size_t)t * HDIM + u] = h_new;
                if (t == TT - 1) out[(size_t)TT * HDIM + HDIM + u] = h_new;
            }

            if (tid >= 448 && t + 1 < TT) {
                const int l = tid - 448;
                const unsigned* f = flags0 + ((t + 1) & 1) * (L0WG * FSTR) + l * FSTR;
                while (__hip_atomic_load(f, __ATOMIC_RELAXED, __HIP_MEMORY_SCOPE_AGENT)
                       < (unsigned)(t + 2)) { }
                const u64* ysrc =
                    reinterpret_cast<const u64*>(ys0 + (size_t)(t + 1) * HDIM);
#pragma unroll
                for (int k = 0; k < 8; ++k) {
                    u64 yv = __hip_atomic_load(ysrc + l * 8 + k, __ATOMIC_RELAXED,
                                               __HIP_MEMORY_SCOPE_AGENT);
                    float2 yf;
                    yf.x = __uint_as_float((unsigned)yv);
                    yf.y = __uint_as_float((unsigned)(yv >> 32));
                    reinterpret_cast<float2*>(lds_y)[l * 8 + k] = yf;
                }
            }

            {
                const unsigned need = (unsigned)(t + 1);
                const u64* hp = h1rep + ((size_t)xcd * 2 + ((t + 1) & 1)) * HDIM;
                u64 v0 = poll_h(hp + 2 * tid, need);
                u64 v1 = poll_h(hp + 2 * tid + 1, need);
                float2 hv;
                hv.x = __uint_as_float((unsigned)v0);
                hv.y = __uint_as_float((unsigned)v1);
                reinterpret_cast<float2*>(lds_h)[tid] = hv;
            }
            __syncthreads();
        }
    }
}

// ---------------- launch ----------------
extern "C" void kernel_launch(void* const* d_in, const int* in_sizes, int n_in,
                              void* d_out, int out_size, void* d_ws, size_t ws_size,
                              hipStream_t stream) {
    const int*   idx = (const int*)d_in[0];
    const float* emb = (const float*)d_in[1];
    const float* wih = (const float*)d_in[2];
    const float* whh = (const float*)d_in[3];
    const float* bih = (const float*)d_in[4];
    const float* bhh = (const float*)d_in[5];
    float* out = (float*)d_out;

    float* x    = (float*)d_ws;                 // [T,H]
    float* gi   = x   + (size_t)TT * HDIM;      // [T,3H]
    float* ys0  = gi  + (size_t)TT * 3 * HDIM;  // [T,H]
    char*  ctrl = (char*)(ys0 + (size_t)TT * HDIM);
    u64* h0rep = (u64*)ctrl;                    // [NREP][2][H]
    u64* h1rep = h0rep + (size_t)NREP * 2 * HDIM;
    unsigned* flags0 = (unsigned*)(h1rep + (size_t)NREP * 2 * HDIM);
    size_t ctrl_bytes = (size_t)(2 * NREP * 2 * HDIM) * 8
                      + (size_t)(2 * L0WG * FSTR) * 4;

    hipMemsetAsync(ctrl, 0, ctrl_bytes, stream);

    embed_kernel<<<TT, 256, 0, stream>>>(idx, emb, x);

    const size_t wstride = (size_t)3 * HDIM * HDIM;
    const size_t bstride = (size_t)3 * HDIM;

    gemm_nt_bias<<<dim3(TT / BM, 3 * HDIM / BN), 256, 0, stream>>>(
        x, wih, bih, gi, TT, 3 * HDIM, HDIM);

    gru_pipe<<<L0WG + L1WG, SBS, 0, stream>>>(
        gi, whh, bhh,
        wih + wstride, whh + wstride, bih + bstride, bhh + bstride,
        ys0, out, h0rep, h1rep, flags0);
}

// Round 12
// 10085.849 us; speedup vs baseline: 3.9757x; 1.5807x over previous
//
#include <hip/hip_runtime.h>
#include <hip/hip_bf16.h>

// v12 = v11 with the exchange critical path shortened:
//  - append-only tagged y0 log (data-in-tag): kills flags0 + per-step
//    __threadfence + ys0 array. L1 stagers poll the log words directly.
//  - concurrent 2-word h polls (issue both, check both, retry both).
//  - conflict-free transposed y staging (lane l <-> elements k*64+l).
// h exchange: 8-replica tagged u64 arrays (v11), consumers poll replica
// [blockIdx&7]. Ring-2 overwrite safety unchanged.

#define TT    4096
#define HDIM  1024
#define L0WG  64
#define L1WG  128
#define SBS   512
#define NREP  8
typedef unsigned long long u64;

// ---------------- embedding gather ----------------
__global__ void embed_kernel(const int* __restrict__ idx,
                             const float* __restrict__ emb,
                             float* __restrict__ x) {
    int t = blockIdx.x;
    int row = idx[t];
    const float4* src = reinterpret_cast<const float4*>(emb + (size_t)row * HDIM);
    float4* dst = reinterpret_cast<float4*>(x + (size_t)t * HDIM);
    dst[threadIdx.x] = src[threadIdx.x];
}

// ---------------- fp32 NT GEMM ----------------
#define BM 64
#define BN 64
#define BK 32
__global__ __launch_bounds__(256)
void gemm_nt_bias(const float* __restrict__ A,
                  const float* __restrict__ Bw,
                  const float* __restrict__ bias,
                  float* __restrict__ C,
                  int M, int N, int K) {
    __shared__ float As[BK][BM];
    __shared__ float Bs[BK][BN];
    const int tid = threadIdx.x;
    const int m0 = blockIdx.x * BM;
    const int n0 = blockIdx.y * BN;
    const int tx = tid & 15, ty = tid >> 4;
    const int lr = tid >> 3;
    const int lc = (tid & 7) * 4;

    float acc[4][4] = {};

    for (int k0 = 0; k0 < K; k0 += BK) {
#pragma unroll
        for (int pass = 0; pass < 2; ++pass) {
            int m = lr + pass * 32;
            float4 v = *reinterpret_cast<const float4*>(A + (size_t)(m0 + m) * K + k0 + lc);
            As[lc + 0][m] = v.x; As[lc + 1][m] = v.y;
            As[lc + 2][m] = v.z; As[lc + 3][m] = v.w;
            float4 u = *reinterpret_cast<const float4*>(Bw + (size_t)(n0 + m) * K + k0 + lc);
            Bs[lc + 0][m] = u.x; Bs[lc + 1][m] = u.y;
            Bs[lc + 2][m] = u.z; Bs[lc + 3][m] = u.w;
        }
        __syncthreads();
#pragma unroll
        for (int kk = 0; kk < BK; ++kk) {
            float4 a = *reinterpret_cast<const float4*>(&As[kk][ty * 4]);
            float4 b = *reinterpret_cast<const float4*>(&Bs[kk][tx * 4]);
            float av[4] = {a.x, a.y, a.z, a.w};
            float bv[4] = {b.x, b.y, b.z, b.w};
#pragma unroll
            for (int i = 0; i < 4; ++i)
#pragma unroll
                for (int j = 0; j < 4; ++j)
                    acc[i][j] = fmaf(av[i], bv[j], acc[i][j]);
        }
        __syncthreads();
    }

    float4 b4 = *reinterpret_cast<const float4*>(bias + n0 + tx * 4);
    float bb[4] = {b4.x, b4.y, b4.z, b4.w};
#pragma unroll
    for (int i = 0; i < 4; ++i) {
        int m = m0 + ty * 4 + i;
        float4 o;
        o.x = acc[i][0] + bb[0];
        o.y = acc[i][1] + bb[1];
        o.z = acc[i][2] + bb[2];
        o.w = acc[i][3] + bb[3];
        *reinterpret_cast<float4*>(C + (size_t)m * N + n0 + tx * 4) = o;
    }
}

// ---------------- helpers ----------------
__device__ __forceinline__ float dot4(float4 a, float4 b) {
    return fmaf(a.x, b.x, fmaf(a.y, b.y, fmaf(a.z, b.z, a.w * b.w)));
}
__device__ __forceinline__ float fsig(float x) { return 1.f / (1.f + __expf(-x)); }
__device__ __forceinline__ float ftanh(float x) {
    return fmaf(-2.f, 1.f / (1.f + __expf(2.f * x)), 1.f);
}
__device__ __forceinline__ u64 pack_h(unsigned seq, float h) {
    return ((u64)seq << 32) | (u64)__float_as_uint(h);
}
__device__ __forceinline__ u64 aload(const u64* p) {
    return __hip_atomic_load(p, __ATOMIC_RELAXED, __HIP_MEMORY_SCOPE_AGENT);
}
__device__ __forceinline__ u64 poll_h(const u64* p, unsigned need) {
    u64 v = aload(p);
    while ((unsigned)(v >> 32) < need) v = aload(p);
    return v;
}
// concurrent two-word poll (both loads in flight each round)
__device__ __forceinline__ void poll2(const u64* p0, const u64* p1, unsigned need,
                                      u64& v0, u64& v1) {
    v0 = aload(p0);
    v1 = aload(p1);
    while ((unsigned)(v0 >> 32) < need || (unsigned)(v1 >> 32) < need) {
        v0 = aload(p0);
        v1 = aload(p1);
    }
}
__device__ __forceinline__ void pub_h(u64* rep, int par, int idx, u64 v) {
#pragma unroll
    for (int r = 0; r < NREP; ++r)
        __hip_atomic_store(rep + ((size_t)r * 2 + par) * HDIM + idx, v,
                           __ATOMIC_RELAXED, __HIP_MEMORY_SCOPE_AGENT);
}
// stage a full y-row from the tagged log into lds (lane l owns k*64+l)
__device__ __forceinline__ void stage_y(const u64* lrow, unsigned need,
                                        float* lds_y, int l) {
    u64 v[16];
#pragma unroll
    for (int k = 0; k < 16; ++k) v[k] = aload(lrow + k * 64 + l);
#pragma unroll
    for (int k = 0; k < 16; ++k)
        while ((unsigned)(v[k] >> 32) < need) v[k] = aload(lrow + k * 64 + l);
#pragma unroll
    for (int k = 0; k < 16; ++k)
        lds_y[k * 64 + l] = __uint_as_float((unsigned)v[k]);
}

// ---------------- fused pipelined scan v12 ----------------
__global__ __launch_bounds__(SBS, 1)
void gru_pipe(const float* __restrict__ gi0,
              const float* __restrict__ whh0,
              const float* __restrict__ bhh0,
              const float* __restrict__ wih1,
              const float* __restrict__ whh1,
              const float* __restrict__ bih1,
              const float* __restrict__ bhh1,
              u64* y0log,                  // [T][HDIM] tagged, append-only
              float* __restrict__ out,     // [T*H + 2H]
              u64* h0rep, u64* h1rep) {    // [NREP][2][HDIM] tagged
    const int tid  = threadIdx.x;
    const int slot = tid >> 3;
    const int l8   = tid & 7;
    const int xcd  = blockIdx.x & 7;

    __shared__ float lds_h[HDIM];
    __shared__ float lds_y[HDIM];
    __shared__ float lds_gh[48];

    if (blockIdx.x < L0WG) {
        // ================= layer 0 =================
        const int g = blockIdx.x;

        float4 Wlo[16], Whi[16];
        if (slot < 48) {
            const int q = slot >> 4, jl = slot & 15;
            const float4* row4 = reinterpret_cast<const float4*>(
                whh0 + (size_t)(q * HDIM + g * 16 + jl) * HDIM);
#pragma unroll
            for (int k4 = 0; k4 < 16; ++k4) Wlo[k4] = row4[k4 * 8 + l8];
#pragma unroll
            for (int k4 = 0; k4 < 16; ++k4) Whi[k4] = row4[(k4 + 16) * 8 + l8];
        } else {
#pragma unroll
            for (int k4 = 0; k4 < 16; ++k4) { Wlo[k4] = float4{0,0,0,0}; Whi[k4] = float4{0,0,0,0}; }
        }

        float bh0 = 0.f, bh1 = 0.f, bh2 = 0.f;
        float gir = 0.f, giz = 0.f, gin = 0.f;
        float h_own = 0.f;
        if (tid < 16) {
            const int gj = g * 16 + tid;
            bh0 = bhh0[0 * HDIM + gj];
            bh1 = bhh0[1 * HDIM + gj];
            bh2 = bhh0[2 * HDIM + gj];
            gir = gi0[gj];
            giz = gi0[HDIM + gj];
            gin = gi0[2 * HDIM + gj];
        }

        lds_h[tid] = 0.f;
        lds_h[tid + SBS] = 0.f;
        __syncthreads();

        const float4* lh4 = reinterpret_cast<const float4*>(lds_h);

        for (int t = 0; t < TT; ++t) {
            float nir = 0.f, niz = 0.f, nin = 0.f;
            if (tid < 16 && t + 1 < TT) {
                const float* base = gi0 + (size_t)(t + 1) * 3 * HDIM + g * 16 + tid;
                nir = base[0];
                niz = base[HDIM];
                nin = base[2 * HDIM];
            }

            if (slot < 48) {
                float p0 = 0.f, p1 = 0.f;
#pragma unroll
                for (int k4 = 0; k4 < 16; ++k4) p0 += dot4(Wlo[k4], lh4[k4 * 8 + l8]);
#pragma unroll
                for (int k4 = 0; k4 < 16; ++k4) p1 += dot4(Whi[k4], lh4[(k4 + 16) * 8 + l8]);
                float p = p0 + p1;
                p += __shfl_xor(p, 1);
                p += __shfl_xor(p, 2);
                p += __shfl_xor(p, 4);
                if (l8 == 0) lds_gh[slot] = p;
            }
            __syncthreads();   // S1

            if (tid < 16) {
                const int gj = g * 16 + tid;
                const float hr = lds_gh[tid]      + bh0;
                const float hz = lds_gh[16 + tid] + bh1;
                const float hn = lds_gh[32 + tid] + bh2;
                const float r = fsig(gir + hr);
                const float z = fsig(giz + hz);
                const float n = ftanh(gin + r * hn);
                const float h_new = (1.f - z) * n + z * h_own;
                h_own = h_new;
                const u64 pk = pack_h((unsigned)(t + 1), h_new);
                pub_h(h0rep, (t + 1) & 1, gj, pk);
                __hip_atomic_store(y0log + (size_t)t * HDIM + gj, pk,
                                   __ATOMIC_RELAXED, __HIP_MEMORY_SCOPE_AGENT);
                if (t == TT - 1) out[(size_t)TT * HDIM + gj] = h_new;
            }

            {
                const unsigned need = (unsigned)(t + 1);
                const u64* hp = h0rep + ((size_t)xcd * 2 + ((t + 1) & 1)) * HDIM;
                u64 v0, v1;
                poll2(hp + 2 * tid, hp + 2 * tid + 1, need, v0, v1);
                float2 hv;
                hv.x = __uint_as_float((unsigned)v0);
                hv.y = __uint_as_float((unsigned)v1);
                reinterpret_cast<float2*>(lds_h)[tid] = hv;
            }
            gir = nir; giz = niz; gin = nin;
            __syncthreads();   // S2
        }
    } else {
        // ================= layer 1 =================
        const int g1 = blockIdx.x - L0WG;

        float4 Wlo[16], Whi[16];
        if (slot < 48) {
            const int ss = (slot < 24) ? slot : slot - 24;
            const int q = ss >> 3, jl = ss & 7;
            const float* mat = (slot < 24) ? whh1 : wih1;
            const float4* row4 = reinterpret_cast<const float4*>(
                mat + (size_t)(q * HDIM + g1 * 8 + jl) * HDIM);
#pragma unroll
            for (int k4 = 0; k4 < 16; ++k4) Wlo[k4] = row4[k4 * 8 + l8];
#pragma unroll
            for (int k4 = 0; k4 < 16; ++k4) Whi[k4] = row4[(k4 + 16) * 8 + l8];
        } else {
#pragma unroll
            for (int k4 = 0; k4 < 16; ++k4) { Wlo[k4] = float4{0,0,0,0}; Whi[k4] = float4{0,0,0,0}; }
        }

        float bh0 = 0.f, bh1 = 0.f, bh2 = 0.f;
        float bi0 = 0.f, bi1 = 0.f, bi2 = 0.f;
        float h_own = 0.f;
        if (tid < 8) {
            const int u = g1 * 8 + tid;
            bh0 = bhh1[0 * HDIM + u];
            bh1 = bhh1[1 * HDIM + u];
            bh2 = bhh1[2 * HDIM + u];
            bi0 = bih1[0 * HDIM + u];
            bi1 = bih1[1 * HDIM + u];
            bi2 = bih1[2 * HDIM + u];
        }

        lds_h[tid] = 0.f;
        lds_h[tid + SBS] = 0.f;
        // prologue: stage y(0) from the tagged log (wave 7)
        if (tid >= 448) {
            stage_y(y0log, 1u, lds_y, tid - 448);
        }
        __syncthreads();

        const float4* lh4 = reinterpret_cast<const float4*>(lds_h);
        const float4* ly4 = reinterpret_cast<const float4*>(lds_y);

        for (int t = 0; t < TT; ++t) {
            if (slot < 48) {
                const float4* s4 = (slot < 24) ? lh4 : ly4;
                float p0 = 0.f, p1 = 0.f;
#pragma unroll
                for (int k4 = 0; k4 < 16; ++k4) p0 += dot4(Wlo[k4], s4[k4 * 8 + l8]);
#pragma unroll
                for (int k4 = 0; k4 < 16; ++k4) p1 += dot4(Whi[k4], s4[(k4 + 16) * 8 + l8]);
                float p = p0 + p1;
                p += __shfl_xor(p, 1);
                p += __shfl_xor(p, 2);
                p += __shfl_xor(p, 4);
                if (l8 == 0) lds_gh[slot] = p;
            }
            __syncthreads();   // S1

            if (tid < 8) {
                const int u = g1 * 8 + tid;
                const float hr = lds_gh[tid]      + bh0;
                const float hz = lds_gh[8 + tid]  + bh1;
                const float hn = lds_gh[16 + tid] + bh2;
                const float ir = lds_gh[24 + tid] + bi0;
                const float iz = lds_gh[32 + tid] + bi1;
                const float in_ = lds_gh[40 + tid] + bi2;
                const float r = fsig(ir + hr);
                const float z = fsig(iz + hz);
                const float n = ftanh(in_ + r * hn);
                const float h_new = (1.f - z) * n + z * h_own;
                h_own = h_new;
                pub_h(h1rep, (t + 1) & 1, u, pack_h((unsigned)(t + 1), h_new));
                out[(size_t)t * HDIM + u] = h_new;
                if (t == TT - 1) out[(size_t)TT * HDIM + HDIM + u] = h_new;
            }

            // wave 7: stage y(t+1) from the tagged log (between S1 and S2)
            if (tid >= 448 && t + 1 < TT) {
                stage_y(y0log + (size_t)(t + 1) * HDIM, (unsigned)(t + 2),
                        lds_y, tid - 448);
            }

            {
                const unsigned need = (unsigned)(t + 1);
                const u64* hp = h1rep + ((size_t)xcd * 2 + ((t + 1) & 1)) * HDIM;
                u64 v0, v1;
                poll2(hp + 2 * tid, hp + 2 * tid + 1, need, v0, v1);
                float2 hv;
                hv.x = __uint_as_float((unsigned)v0);
                hv.y = __uint_as_float((unsigned)v1);
                reinterpret_cast<float2*>(lds_h)[tid] = hv;
            }
            __syncthreads();   // S2
        }
    }
}

// ---------------- launch ----------------
extern "C" void kernel_launch(void* const* d_in, const int* in_sizes, int n_in,
                              void* d_out, int out_size, void* d_ws, size_t ws_size,
                              hipStream_t stream) {
    const int*   idx = (const int*)d_in[0];
    const float* emb = (const float*)d_in[1];
    const float* wih = (const float*)d_in[2];
    const float* whh = (const float*)d_in[3];
    const float* bih = (const float*)d_in[4];
    const float* bhh = (const float*)d_in[5];
    float* out = (float*)d_out;

    float* x     = (float*)d_ws;                 // [T,H]
    float* gi    = x  + (size_t)TT * HDIM;       // [T,3H]
    u64*   y0log = (u64*)(gi + (size_t)TT * 3 * HDIM);   // [T][H] tagged
    u64*   h0rep = y0log + (size_t)TT * HDIM;            // [NREP][2][H]
    u64*   h1rep = h0rep + (size_t)NREP * 2 * HDIM;      // [NREP][2][H]
    // y0log + replicas must be zeroed every call (tags are compared >=)
    size_t zero_bytes = ((size_t)TT * HDIM + 2 * (size_t)NREP * 2 * HDIM) * 8;

    hipMemsetAsync(y0log, 0, zero_bytes, stream);

    embed_kernel<<<TT, 256, 0, stream>>>(idx, emb, x);

    const size_t wstride = (size_t)3 * HDIM * HDIM;
    const size_t bstride = (size_t)3 * HDIM;

    gemm_nt_bias<<<dim3(TT / BM, 3 * HDIM / BN), 256, 0, stream>>>(
        x, wih, bih, gi, TT, 3 * HDIM, HDIM);

    gru_pipe<<<L0WG + L1WG, SBS, 0, stream>>>(
        gi, whh, bhh,
        wih + wstride, whh + wstride, bih + bstride, bhh + bstride,
        y0log, out, h0rep, h1rep);
}